// Round 3
// baseline (1648.106 us; speedup 1.0000x reference)
//
#include <hip/hip_runtime.h>
#include <stdint.h>

#define NDATA 200000
#define BATCH 256
#define BITD  64
#define TOPF  20
#define KNEG  2500
#define RANKA 20000            // N_DATA - HIGH
#define TVAL  7.2f
#define S8T   (8.0f/7.2f)
#define THRV  0.3f
#define TAU   0.976f
#define KHINV 42666.666f       // 1024/(1-TAU)

#define NB    512
#define HLO   (-0.35f)
#define HINV  1024.0f

#define CF    2048             // fnp candidate cap (sim > 0.3)
#define CN    6144             // neg candidate cap (key > TAU)

#define WCH   8                // iterations of 128 rows per WG
#define NCH   196              // 196*1024 = 200704 >= 200000
#define NSB   8                // sample blocks of 32

typedef unsigned long long u64;
typedef __attribute__((ext_vector_type(16))) float f32x16;
typedef __attribute__((ext_vector_type(8))) short s16x8;

__device__ __forceinline__ int binOf(float sim) {
    int b = (int)floorf((sim - HLO) * HINV);
    b = b < 0 ? 0 : b;
    b = b > (NB - 1) ? (NB - 1) : b;
    return b;
}
__device__ __forceinline__ unsigned short bf16_rne(float x) {
    unsigned u = __float_as_uint(x);
    unsigned r = (u + 0x7FFFu + ((u >> 16) & 1u)) >> 16;
    return (unsigned short)r;
}

// ---------------------------------------------------------------- kernel A
__global__ __launch_bounds__(64) void k_prep(
    const float* __restrict__ iA, const float* __restrict__ iB,
    const float* __restrict__ tA, const float* __restrict__ tB,
    const float* __restrict__ mem, const int* __restrict__ bidx,
    unsigned short* __restrict__ fsumHi, unsigned short* __restrict__ fsumLo,
    float* __restrict__ f1_g, float* __restrict__ upd_g,
    float* __restrict__ posExp_g,
    unsigned* __restrict__ fnpCnt, unsigned* __restrict__ negCnt,
    unsigned* __restrict__ hist_gp)
{
    int s = blockIdx.x, j = threadIdx.x;
    float a = iA[s * BITD + j], b = iB[s * BITD + j];
    float c = tA[s * BITD + j], d = tB[s * BITD + j];
    float f1 = 0.5f * (a + c), f2 = 0.5f * (a + d);
    float f3 = 0.5f * (b + c), f4 = 0.5f * (b + d);
    float q1 = f1 * f1, q2 = f2 * f2, q3 = f3 * f3, q4 = f4 * f4;
#pragma unroll
    for (int m = 1; m < 64; m <<= 1) {
        q1 += __shfl_xor(q1, m); q2 += __shfl_xor(q2, m);
        q3 += __shfl_xor(q3, m); q4 += __shfl_xor(q4, m);
    }
    float n1 = sqrtf(q1), n2 = sqrtf(q2), n3 = sqrtf(q3), n4 = sqrtf(q4);
    float fs = 0.25f * (f1 / n1 + f2 / n2 + f3 / n3 + f4 / n4);

    unsigned short hi = bf16_rne(fs);
    float hif = __uint_as_float(((unsigned)hi) << 16);
    unsigned short lo = bf16_rne(fs - hif);
    fsumHi[s * BITD + j] = hi;
    fsumLo[s * BITD + j] = lo;
    f1_g[s * BITD + j] = f1;

    int pos = bidx[s];
    float mv = mem[(size_t)pos * BITD + j];
    float sg = (mv > 0.f) ? 1.f : ((mv < 0.f) ? -1.f : 0.f);
    float ps = sg * f1;
#pragma unroll
    for (int m = 1; m < 64; m <<= 1) ps += __shfl_xor(ps, m);

    float nf = f1 / n1;
    float u = mv * 0.4f + nf * 0.6f;
    float uq = u * u;
#pragma unroll
    for (int m = 1; m < 64; m <<= 1) uq += __shfl_xor(uq, m);
    upd_g[s * BITD + j] = u / sqrtf(uq);

    if (j == 0) {
        posExp_g[s] = expf(ps / TVAL);
        fnpCnt[s] = 0u; negCnt[s] = 0u;
    }
    // zero the packed histogram: 65536 words total, 256 per block
    for (int k = j; k < 256; k += 64) hist_gp[s * 256 + k] = 0u;
}

// ---------------------------------------------------------------- kernel P (pack mem -> bf16 B-fragments)
// layout: element index  ((t2*4 + ks)*2 + h)*256 + sl*8 + e
//         = mem[t2*32 + sl][ks*16 + 8*h + e]  as bf16
__global__ __launch_bounds__(256) void k_pack(const float* __restrict__ mem,
                                              unsigned short* __restrict__ memB)
{
    int t2 = blockIdx.x;
    int t = threadIdx.x;
    int sl = t & 31, h = (t >> 5) & 1, ks = t >> 6;
    const float* src = mem + (size_t)(t2 * 32 + sl) * BITD + ks * 16 + 8 * h;
    float4 v0 = *(const float4*)src;
    float4 v1 = *(const float4*)(src + 4);
    s16x8 o;
    o[0] = (short)bf16_rne(v0.x); o[1] = (short)bf16_rne(v0.y);
    o[2] = (short)bf16_rne(v0.z); o[3] = (short)bf16_rne(v0.w);
    o[4] = (short)bf16_rne(v1.x); o[5] = (short)bf16_rne(v1.y);
    o[6] = (short)bf16_rne(v1.z); o[7] = (short)bf16_rne(v1.w);
    *(s16x8*)(memB + ((size_t)(t2 * 4 + ks) * 2 + h) * 256 + sl * 8) = o;
}

// ---------------------------------------------------------------- kernel B (MFMA main pass, transposed)
__global__ __launch_bounds__(256, 4) void k_main(
    const unsigned short* __restrict__ memB, const float* __restrict__ ru,
    const unsigned short* __restrict__ fsumHi, const unsigned short* __restrict__ fsumLo,
    unsigned* __restrict__ fnpCnt, unsigned* __restrict__ negCnt,
    u64* __restrict__ fnpPack, u64* __restrict__ negPack,
    unsigned* __restrict__ hist_gp)
{
    __shared__ unsigned histL[8 * NB];   // [smp>>2][bin], u8 lanes by smp&3

    const int tid = threadIdx.x;
    const int w = tid >> 6, l = tid & 63;
    const int h = l >> 5, sl = l & 31;
    const int sbBase = blockIdx.y * 32;
    const int chunkBase = blockIdx.x * (WCH * 128);

    for (int q = tid; q < 8 * NB; q += 256) histL[q] = 0u;
    __syncthreads();

    // A fragments (fsum hi/lo): lane sl holds sample sbBase+sl, k-slice 8*h
    s16x8 aHi[4], aLo[4];
    {
        const unsigned short* ph = fsumHi + (size_t)(sbBase + sl) * BITD + 8 * h;
        const unsigned short* pl = fsumLo + (size_t)(sbBase + sl) * BITD + 8 * h;
#pragma unroll
        for (int ks = 0; ks < 4; ++ks) {
            aHi[ks] = *(const s16x8*)(ph + ks * 16);
            aLo[ks] = *(const s16x8*)(pl + ks * 16);
        }
    }
    const s16x8* bp = (const s16x8*)memB;

    // prefetch B frags for first tile
    s16x8 bcur[4], bnxt[4];
    {
        int waveRow = chunkBase + 32 * w;
        int t2 = (waveRow < NDATA) ? (waveRow >> 5) : 0;
#pragma unroll
        for (int ks = 0; ks < 4; ++ks)
            bcur[ks] = bp[((size_t)(t2 * 4 + ks) * 2 + h) * 32 + sl];
    }

    for (int it = 0; it < WCH; ++it) {
        const int waveRow = chunkBase + it * 128 + 32 * w;
        const bool valid = (waveRow < NDATA);

        // issue ru loads early (coalesced dwords; lane sl -> row waveRow+sl)
        float kk[16];
        if (valid) {
#pragma unroll
            for (int i = 0; i < 16; ++i) {
                int smp = (i & 3) + 8 * (i >> 2) + 4 * h;
                kk[i] = ru[(size_t)(sbBase + smp) * NDATA + waveRow + sl];
            }
        }

        // prefetch next tile's B frags
        {
            int nRow = chunkBase + (it + 1) * 128 + 32 * w;
            int t2 = (it + 1 < WCH && nRow < NDATA) ? (nRow >> 5) : 0;
#pragma unroll
            for (int ks = 0; ks < 4; ++ks)
                bnxt[ks] = bp[((size_t)(t2 * 4 + ks) * 2 + h) * 32 + sl];
        }

        if (valid) {
            f32x16 acc;
#pragma unroll
            for (int i = 0; i < 16; ++i) acc[i] = 0.f;
#pragma unroll
            for (int ks = 0; ks < 4; ++ks) {
                acc = __builtin_amdgcn_mfma_f32_32x32x16_bf16(aHi[ks], bcur[ks], acc, 0, 0, 0);
                acc = __builtin_amdgcn_mfma_f32_32x32x16_bf16(aLo[ks], bcur[ks], acc, 0, 0, 0);
            }

            const int grow = waveRow + sl;   // this lane's mem row (col = lane&31)
#pragma unroll
            for (int i = 0; i < 16; ++i) {
                float sim = acc[i];
                int smp = (i & 3) + 8 * (i >> 2) + 4 * h;  // uniform across wave
                int sg = sbBase + smp;
                int bin = binOf(sim);
                atomicAdd(&histL[(smp >> 2) * NB + bin], 1u << (8 * (i & 3)));

                bool pf = sim > THRV;
                u64 mF = __ballot(pf);
                if (pf) {
                    int ldr = __builtin_ctzll(mF);
                    unsigned base = 0;
                    if (l == ldr) base = atomicAdd(&fnpCnt[sg], (unsigned)__popcll(mF));
                    base = __shfl(base, ldr);
                    unsigned idx = base + (unsigned)__popcll(mF & ((1ull << l) - 1ull));
                    if (idx < CF)
                        fnpPack[(size_t)sg * CF + idx] =
                            ((u64)__float_as_uint(sim) << 32) | (u64)(0x3FFFFu - (unsigned)grow);
                }
                bool pn = kk[i] > TAU;
                u64 mN = __ballot(pn);
                if (pn) {
                    int ldr = __builtin_ctzll(mN);
                    unsigned base = 0;
                    if (l == ldr) base = atomicAdd(&negCnt[sg], (unsigned)__popcll(mN));
                    base = __shfl(base, ldr);
                    unsigned idx = base + (unsigned)__popcll(mN & ((1ull << l) - 1ull));
                    if (idx < CN)
                        negPack[(size_t)sg * CN + idx] =
                            ((u64)__float_as_uint(kk[i]) << 32) |
                            ((u64)(0x3FFFFu - (unsigned)grow) << 9) | (u64)bin;
                }
            }
        }
#pragma unroll
        for (int ks = 0; ks < 4; ++ks) bcur[ks] = bnxt[ks];
    }

    __syncthreads();
    // merge u8 histogram to global packed-u16 sample pairs
    for (int q = tid; q < 8 * NB; q += 256) {
        int g = q >> 9, bin = q & (NB - 1);
        unsigned wv = histL[g * NB + bin];
        if (!wv) continue;
        unsigned c0 = wv & 0xffu, c1 = (wv >> 8) & 0xffu;
        unsigned c2 = (wv >> 16) & 0xffu, c3 = wv >> 24;
        int sBase = sbBase + g * 4;          // even
        unsigned p01 = c0 | (c1 << 16), p23 = c2 | (c3 << 16);
        if (p01) atomicAdd(&hist_gp[(size_t)(sBase >> 1) * NB + bin], p01);
        if (p23) atomicAdd(&hist_gp[(size_t)((sBase >> 1) + 1) * NB + bin], p23);
    }
}

// ---------------------------------------------------------------- kernel C (per-sample finalize)
__global__ __launch_bounds__(256) void k_fin(
    const int* __restrict__ bidx,
    const unsigned* __restrict__ fnpCnt, const unsigned* __restrict__ negCnt,
    const u64* __restrict__ fnpPack, const u64* __restrict__ negPack,
    const unsigned* __restrict__ hist_gp, const float* __restrict__ posExp_g,
    const float* __restrict__ f1_g, const float* __restrict__ mem,
    float* __restrict__ losses)
{
    __shared__ u64 arrF[CF];
    __shared__ unsigned khist[1024];
    __shared__ unsigned incl[2512];
    __shared__ u64 bnd[64];
    __shared__ u64 winPk[TOPF];
    __shared__ unsigned exclR[TOPF];
    __shared__ float numW[TOPF];
    __shared__ float f1sh[BITD];
    __shared__ unsigned scr[NB];
    __shared__ unsigned scanBuf[256];
    __shared__ float redF[256];
    __shared__ u64 wmaxS[4];
    __shared__ u64 shBest;
    __shared__ int shI[4];
    __shared__ float shNum;
    __shared__ unsigned bndCnt;

    const int s = blockIdx.x, tid = threadIdx.x;
    const int w = tid >> 6, l = tid & 63;
    const int pos = bidx[s];

    if (tid < 16) *(float4*)&f1sh[tid * 4] = *(const float4*)&f1_g[(size_t)s * BITD + tid * 4];
    if (tid == 0) bndCnt = 0u;
    {
        int sh = (s & 1) * 16;
        unsigned w0 = hist_gp[(size_t)(s >> 1) * NB + tid];
        unsigned w1 = hist_gp[(size_t)(s >> 1) * NB + tid + 256];
        scr[tid] = (w0 >> sh) & 0xffffu;
        scr[tid + 256] = (w1 >> sh) & 0xffffu;
    }
    __syncthreads();

    if (tid == 0) {
        unsigned cum = 0; int beta = NB - 1;
        for (int b2 = 0; b2 < NB; ++b2) {
            cum += scr[b2];
            if (cum >= (unsigned)(RANKA + 1)) { beta = b2; break; }
        }
        shI[0] = beta;
    }

    // ---- fnp top-20 by (sim desc, row asc) via 20 argmax extractions
    unsigned cf = fnpCnt[s]; if (cf > CF) cf = CF;
    for (int i = tid; i < (int)cf; i += 256) arrF[i] = fnpPack[(size_t)s * CF + i];
    __syncthreads();

    for (int wi = 0; wi < TOPF; ++wi) {
        u64 m = 0;
        for (int i = tid; i < (int)cf; i += 256) { u64 v = arrF[i]; m = v > m ? v : m; }
#pragma unroll
        for (int off = 1; off < 64; off <<= 1) { u64 o = __shfl_xor(m, off); m = o > m ? o : m; }
        if (l == 0) wmaxS[w] = m;
        __syncthreads();
        if (tid == 0) {
            u64 best = wmaxS[0];
            if (wmaxS[1] > best) best = wmaxS[1];
            if (wmaxS[2] > best) best = wmaxS[2];
            if (wmaxS[3] > best) best = wmaxS[3];
            winPk[wi] = best; shBest = best;
        }
        __syncthreads();
        u64 best = shBest;
        if (best == 0ull) break;
        for (int i = tid; i < (int)cf; i += 256) if (arrF[i] == best) arrF[i] = 0ull;
        __syncthreads();
    }
    __syncthreads();
    if (tid == 0) {
        int ne = 0;
        for (int wi = 0; wi < TOPF; ++wi) {
            u64 pk = winPk[wi];
            if (pk == 0ull) break;
            unsigned row = 0x3FFFFu - (unsigned)(pk & 0x3FFFFull);
            if ((int)row != pos) exclR[ne++] = row;
        }
        shI[1] = ne;
    }
    __syncthreads();
    const int beta = shI[0], ne = shI[1];

    // e-dots for valid winners (4 lanes per entry)
    {
        int grp = tid >> 2, lp = tid & 3;
        if (grp < ne) {
            unsigned row = exclR[grp];
            const float* mr = mem + (size_t)row * BITD + lp * 16;
            const float* fr = &f1sh[lp * 16];
            float part = 0.f;
#pragma unroll
            for (int m2 = 0; m2 < 16; ++m2) part = fmaf(mr[m2], fr[m2], part);
            part += __shfl_xor(part, 1);
            part += __shfl_xor(part, 2);
            if (lp == 0) {
                float fsim = part * S8T;
                numW[grp] = fsim * expf(fsim);
            }
        }
    }
    __syncthreads();
    if (tid == 0) {
        float numer = posExp_g[s];
        for (int g = 0; g < ne; ++g) numer += numW[g];
        shNum = numer;
    }

    // ---- negatives: top-2500 keys among filtered candidates
    unsigned cn = negCnt[s]; if (cn > CN) cn = CN;
    for (int q = tid; q < 1024; q += 256) khist[q] = 0u;
    __syncthreads();

    // pass A: key histogram of filtered entries
    for (int i = tid; i < (int)cn; i += 256) {
        u64 v = negPack[(size_t)s * CN + i];
        int bin = (int)(v & 511ull);
        if (bin < beta) continue;
        unsigned row = 0x3FFFFu - (unsigned)((v >> 9) & 0x3FFFFull);
        if ((int)row == pos) continue;
        bool ex = false;
        for (int q2 = 0; q2 < ne; ++q2) ex = ex || (exclR[q2] == row);
        if (ex) continue;
        float key = __uint_as_float((unsigned)(v >> 32));
        int kb = (int)((key - TAU) * KHINV);
        kb = kb < 0 ? 0 : (kb > 1023 ? 1023 : kb);
        atomicAdd(&khist[kb], 1u);
    }
    __syncthreads();
    if (tid == 0) {
        unsigned acc2 = 0; int Bs = 0;
        for (int b2 = 1023; b2 >= 0; --b2) {
            unsigned c2 = khist[b2];
            if (acc2 + c2 >= (unsigned)KNEG) { Bs = b2; break; }
            acc2 += c2;
            if (b2 == 0) Bs = 0;
        }
        shI[2] = Bs;
    }
    __syncthreads();
    const int Bstar = shI[2];

    // pass B1: per-thread counts of strictly-above entries
    unsigned cnt = 0;
    for (int i = tid; i < (int)cn; i += 256) {
        u64 v = negPack[(size_t)s * CN + i];
        int bin = (int)(v & 511ull);
        if (bin < beta) continue;
        unsigned row = 0x3FFFFu - (unsigned)((v >> 9) & 0x3FFFFull);
        if ((int)row == pos) continue;
        bool ex = false;
        for (int q2 = 0; q2 < ne; ++q2) ex = ex || (exclR[q2] == row);
        if (ex) continue;
        float key = __uint_as_float((unsigned)(v >> 32));
        int kb = (int)((key - TAU) * KHINV);
        kb = kb < 0 ? 0 : (kb > 1023 ? 1023 : kb);
        if (kb > Bstar) cnt++;
    }
    scanBuf[tid] = cnt;
    __syncthreads();
    if (tid == 0) {
        unsigned run = 0;
        for (int q2 = 0; q2 < 256; ++q2) { unsigned t3 = scanBuf[q2]; scanBuf[q2] = run; run += t3; }
        shI[3] = (int)run;   // C1tot
    }
    __syncthreads();

    // pass B2: place above-entries (deterministic), gather boundary-bin entries
    {
        unsigned off2 = scanBuf[tid];
        for (int i = tid; i < (int)cn; i += 256) {
            u64 v = negPack[(size_t)s * CN + i];
            int bin = (int)(v & 511ull);
            if (bin < beta) continue;
            unsigned row = 0x3FFFFu - (unsigned)((v >> 9) & 0x3FFFFull);
            if ((int)row == pos) continue;
            bool ex = false;
            for (int q2 = 0; q2 < ne; ++q2) ex = ex || (exclR[q2] == row);
            if (ex) continue;
            float key = __uint_as_float((unsigned)(v >> 32));
            int kb = (int)((key - TAU) * KHINV);
            kb = kb < 0 ? 0 : (kb > 1023 ? 1023 : kb);
            if (kb > Bstar) {
                incl[off2++] = row;
            } else if (kb == Bstar) {
                unsigned sl2 = atomicAdd(&bndCnt, 1u);
                if (sl2 < 64u) bnd[sl2] = v;
            }
        }
    }
    __syncthreads();
    if (tid == 0) {
        int C1 = shI[3];
        int m = KNEG - C1;
        int bc = (int)bndCnt; if (bc > 64) bc = 64;
        if (m > bc) m = bc;
        if (m < 0) m = 0;
        for (int t2 = 0; t2 < m; ++t2) {          // exact top-m of boundary bin
            u64 best = 0; int bi = -1;
            for (int q2 = 0; q2 < bc; ++q2)
                if (bnd[q2] > best) { best = bnd[q2]; bi = q2; }
            incl[C1 + t2] = 0x3FFFFu - (unsigned)((best >> 9) & 0x3FFFFull);
            bnd[bi] = 0;
        }
        shI[3] = C1 + m;   // nInc
    }
    __syncthreads();
    const int nInc = shI[3];

    // denominator: e-dots over included rows (4 lanes per entry)
    float dpart = 0.f;
    {
        int grp = tid >> 2, lp = tid & 3;
        float f1r[16];
#pragma unroll
        for (int m2 = 0; m2 < 16; ++m2) f1r[m2] = f1sh[lp * 16 + m2];
        for (int e2 = grp; e2 < nInc; e2 += 64) {
            unsigned row = incl[e2];
            const float* mr = mem + (size_t)row * BITD + lp * 16;
            float part = 0.f;
#pragma unroll
            for (int m2 = 0; m2 < 16; ++m2) part = fmaf(mr[m2], f1r[m2], part);
            part += __shfl_xor(part, 1);
            part += __shfl_xor(part, 2);
            if (lp == 0) dpart += expf(part * S8T);
        }
    }
    redF[tid] = dpart;
    __syncthreads();
    for (int st = 128; st > 0; st >>= 1) {
        if (tid < st) redF[tid] += redF[tid + st];
        __syncthreads();
    }
    if (tid == 0) {
        float D = redF[0] + posExp_g[s];
        losses[s] = -logf(shNum / D) / (1.0f + (float)ne);
    }
}

// ---------------------------------------------------------------- small kernels
__global__ __launch_bounds__(256) void k_loss(const float* __restrict__ losses,
                                              float* __restrict__ out)
{
    __shared__ float buf[256];
    int t = threadIdx.x;
    buf[t] = losses[t];
    __syncthreads();
    for (int st = 128; st > 0; st >>= 1) {
        if (t < st) buf[t] += buf[t + st];
        __syncthreads();
    }
    if (t == 0) out[0] = buf[0] / 256.0f;
}

__global__ __launch_bounds__(256) void k_copy(const float* __restrict__ mem,
                                              float* __restrict__ out)
{
    size_t i = ((size_t)blockIdx.x * 256 + threadIdx.x) * 4;
    if (i < (size_t)NDATA * BITD) {
        float4 v = *(const float4*)&mem[i];
        out[1 + i] = v.x; out[2 + i] = v.y; out[3 + i] = v.z; out[4 + i] = v.w;
    }
}

__global__ __launch_bounds__(64) void k_scatter(const int* __restrict__ bidx,
                                                const float* __restrict__ upd,
                                                float* __restrict__ out)
{
    int s = blockIdx.x, j = threadIdx.x;
    int pos = bidx[s];
    bool last = true;
    for (int s2 = s + 1; s2 < BATCH; ++s2)
        if (bidx[s2] == pos) last = false;   // last write wins (np semantics)
    if (last) out[1 + (size_t)pos * BITD + j] = upd[s * BITD + j];
}

// ---------------------------------------------------------------- launcher
extern "C" void kernel_launch(void* const* d_in, const int* in_sizes, int n_in,
                              void* d_out, int out_size, void* d_ws, size_t ws_size,
                              hipStream_t stream)
{
    const float* iA = (const float*)d_in[0];
    const float* iB = (const float*)d_in[1];
    const float* tA = (const float*)d_in[2];
    const float* tB = (const float*)d_in[3];
    const float* mem = (const float*)d_in[4];
    const float* ru  = (const float*)d_in[5];
    const int* bidx  = (const int*)d_in[6];
    float* out = (float*)d_out;

    char* w = (char*)d_ws;
    u64* fnpPack = (u64*)w;          w += (size_t)BATCH * CF * 8;      // 4 MB
    u64* negPack = (u64*)w;          w += (size_t)BATCH * CN * 8;      // 12.6 MB
    unsigned short* memB = (unsigned short*)w; w += (size_t)NDATA * BITD * 2;  // 25.6 MB
    float* f1_g = (float*)w;         w += BATCH * BITD * 4;
    float* upd_g = (float*)w;        w += BATCH * BITD * 4;
    float* posExp_g = (float*)w;     w += BATCH * 4;
    float* losses = (float*)w;       w += BATCH * 4;
    unsigned* fnpCnt = (unsigned*)w; w += BATCH * 4;
    unsigned* negCnt = (unsigned*)w; w += BATCH * 4;
    unsigned* hist_gp = (unsigned*)w; w += (size_t)(BATCH / 2) * NB * 4;  // 256 KB
    unsigned short* fsumHi = (unsigned short*)w; w += BATCH * BITD * 2;
    unsigned short* fsumLo = (unsigned short*)w; w += BATCH * BITD * 2;

    k_prep<<<BATCH, 64, 0, stream>>>(iA, iB, tA, tB, mem, bidx, fsumHi, fsumLo,
                                     f1_g, upd_g, posExp_g, fnpCnt, negCnt, hist_gp);
    k_pack<<<NDATA / 32, 256, 0, stream>>>(mem, memB);
    k_copy<<<(NDATA * BITD) / 4 / 256, 256, 0, stream>>>(mem, out);
    k_main<<<dim3(NCH, NSB), 256, 0, stream>>>(memB, ru, fsumHi, fsumLo,
                                               fnpCnt, negCnt, fnpPack, negPack, hist_gp);
    k_fin<<<BATCH, 256, 0, stream>>>(bidx, fnpCnt, negCnt, fnpPack, negPack,
                                     hist_gp, posExp_g, f1_g, mem, losses);
    k_loss<<<1, 256, 0, stream>>>(losses, out);
    k_scatter<<<BATCH, 64, 0, stream>>>(bidx, upd_g, out);
}

// Round 4
// 484.696 us; speedup vs baseline: 3.4003x; 3.4003x over previous
//
#include <hip/hip_runtime.h>
#include <stdint.h>

#define NDATA 200000
#define BATCH 256
#define BITD  64
#define TOPF  20
#define KNEG  2500
#define RANKA 20000            // N_DATA - HIGH
#define TVAL  7.2f
#define S8T   (8.0f/7.2f)
#define THRV  0.3f
#define TAU   0.976f
#define KHINV 42666.666f       // 1024/(1-TAU)

#define NB    512
#define HLO   (-0.35f)
#define HINV  1024.0f

#define NBLK  6250             // NDATA/32 mask words per sample
#define CFX   2048             // fnp candidate cap
#define CNX   6144             // neg candidate cap

#define WCH   8                // iterations of 128 rows per WG
#define NCH   196              // 196*1024 = 200704 >= 200000
#define NSB   8                // sample blocks of 32
#define BLKF  512

typedef unsigned long long u64;
typedef __attribute__((ext_vector_type(16))) float f32x16;
typedef __attribute__((ext_vector_type(8))) short s16x8;

__device__ __forceinline__ int binOf(float sim) {
    int b = (int)floorf((sim - HLO) * HINV);
    b = b < 0 ? 0 : b;
    b = b > (NB - 1) ? (NB - 1) : b;
    return b;
}
__device__ __forceinline__ unsigned short bf16_rne(float x) {
    unsigned u = __float_as_uint(x);
    unsigned r = (u + 0x7FFFu + ((u >> 16) & 1u)) >> 16;
    return (unsigned short)r;
}

// ---------------------------------------------------------------- kernel A
__global__ __launch_bounds__(64) void k_prep(
    const float* __restrict__ iA, const float* __restrict__ iB,
    const float* __restrict__ tA, const float* __restrict__ tB,
    const float* __restrict__ mem, const int* __restrict__ bidx,
    unsigned short* __restrict__ fsumHi, unsigned short* __restrict__ fsumLo,
    float* __restrict__ fsumF, float* __restrict__ f1_g,
    float* __restrict__ upd_g, float* __restrict__ posExp_g,
    unsigned* __restrict__ hist_gp)
{
    int s = blockIdx.x, j = threadIdx.x;
    float a = iA[s * BITD + j], b = iB[s * BITD + j];
    float c = tA[s * BITD + j], d = tB[s * BITD + j];
    float f1 = 0.5f * (a + c), f2 = 0.5f * (a + d);
    float f3 = 0.5f * (b + c), f4 = 0.5f * (b + d);
    float q1 = f1 * f1, q2 = f2 * f2, q3 = f3 * f3, q4 = f4 * f4;
#pragma unroll
    for (int m = 1; m < 64; m <<= 1) {
        q1 += __shfl_xor(q1, m); q2 += __shfl_xor(q2, m);
        q3 += __shfl_xor(q3, m); q4 += __shfl_xor(q4, m);
    }
    float n1 = sqrtf(q1), n2 = sqrtf(q2), n3 = sqrtf(q3), n4 = sqrtf(q4);
    float fs = 0.25f * (f1 / n1 + f2 / n2 + f3 / n3 + f4 / n4);

    unsigned short hi = bf16_rne(fs);
    float hif = __uint_as_float(((unsigned)hi) << 16);
    unsigned short lo = bf16_rne(fs - hif);
    fsumHi[s * BITD + j] = hi;
    fsumLo[s * BITD + j] = lo;
    fsumF[s * BITD + j] = fs;
    f1_g[s * BITD + j] = f1;

    int pos = bidx[s];
    float mv = mem[(size_t)pos * BITD + j];
    float sg = (mv > 0.f) ? 1.f : ((mv < 0.f) ? -1.f : 0.f);
    float ps = sg * f1;
#pragma unroll
    for (int m = 1; m < 64; m <<= 1) ps += __shfl_xor(ps, m);

    float nf = f1 / n1;
    float u = mv * 0.4f + nf * 0.6f;
    float uq = u * u;
#pragma unroll
    for (int m = 1; m < 64; m <<= 1) uq += __shfl_xor(uq, m);
    upd_g[s * BITD + j] = u / sqrtf(uq);

    if (j == 0) posExp_g[s] = expf(ps / TVAL);
    // zero packed histogram: 256 words per sample
    for (int k = j; k < 256; k += 64) hist_gp[s * 256 + k] = 0u;
}

// ---------------------------------------------------------------- kernel P (pack mem -> bf16 B-fragments)
__global__ __launch_bounds__(256) void k_pack(const float* __restrict__ mem,
                                              unsigned short* __restrict__ memB)
{
    int t2 = blockIdx.x;
    int t = threadIdx.x;
    int sl = t & 31, h = (t >> 5) & 1, ks = t >> 6;
    const float* src = mem + (size_t)(t2 * 32 + sl) * BITD + ks * 16 + 8 * h;
    float4 v0 = *(const float4*)src;
    float4 v1 = *(const float4*)(src + 4);
    s16x8 o;
    o[0] = (short)bf16_rne(v0.x); o[1] = (short)bf16_rne(v0.y);
    o[2] = (short)bf16_rne(v0.z); o[3] = (short)bf16_rne(v0.w);
    o[4] = (short)bf16_rne(v1.x); o[5] = (short)bf16_rne(v1.y);
    o[6] = (short)bf16_rne(v1.z); o[7] = (short)bf16_rne(v1.w);
    *(s16x8*)(memB + ((size_t)(t2 * 4 + ks) * 2 + h) * 256 + sl * 8) = o;
}

// ---------------------------------------------------------------- kernel B (MFMA + histogram + masks)
__global__ __launch_bounds__(256, 4) void k_main(
    const unsigned short* __restrict__ memB, const float* __restrict__ ru,
    const unsigned short* __restrict__ fsumHi, const unsigned short* __restrict__ fsumLo,
    unsigned* __restrict__ fnpMask, unsigned* __restrict__ negMask,
    unsigned* __restrict__ hist_gp)
{
    __shared__ unsigned histL[8 * NB];   // [smp>>2][bin], u8 lanes by smp&3

    const int tid = threadIdx.x;
    const int w = tid >> 6, l = tid & 63;
    const int h = l >> 5, sl = l & 31;
    const int sbBase = blockIdx.y * 32;
    const int chunkBase = blockIdx.x * (WCH * 128);

    for (int q = tid; q < 8 * NB; q += 256) histL[q] = 0u;
    __syncthreads();

    // A fragments (fsum hi/lo): lane sl holds sample sbBase+sl, k-slice 8*h
    s16x8 aHi[4], aLo[4];
    {
        const unsigned short* ph = fsumHi + (size_t)(sbBase + sl) * BITD + 8 * h;
        const unsigned short* pl = fsumLo + (size_t)(sbBase + sl) * BITD + 8 * h;
#pragma unroll
        for (int ks = 0; ks < 4; ++ks) {
            aHi[ks] = *(const s16x8*)(ph + ks * 16);
            aLo[ks] = *(const s16x8*)(pl + ks * 16);
        }
    }
    const s16x8* bp = (const s16x8*)memB;

    s16x8 bcur[4], bnxt[4];
    {
        int waveRow = chunkBase + 32 * w;
        int t2 = (waveRow < NDATA) ? (waveRow >> 5) : 0;
#pragma unroll
        for (int ks = 0; ks < 4; ++ks)
            bcur[ks] = bp[((size_t)(t2 * 4 + ks) * 2 + h) * 32 + sl];
    }

    for (int it = 0; it < WCH; ++it) {
        const int waveRow = chunkBase + it * 128 + 32 * w;
        const bool valid = (waveRow < NDATA);

        float kk[16];
        if (valid) {
#pragma unroll
            for (int i = 0; i < 16; ++i) {
                int smp = (i & 3) + 8 * (i >> 2) + 4 * h;
                kk[i] = ru[(size_t)(sbBase + smp) * NDATA + waveRow + sl];
            }
        }
        {
            int nRow = chunkBase + (it + 1) * 128 + 32 * w;
            int t2 = (it + 1 < WCH && nRow < NDATA) ? (nRow >> 5) : 0;
#pragma unroll
            for (int ks = 0; ks < 4; ++ks)
                bnxt[ks] = bp[((size_t)(t2 * 4 + ks) * 2 + h) * 32 + sl];
        }

        if (valid) {
            f32x16 acc;
#pragma unroll
            for (int i = 0; i < 16; ++i) acc[i] = 0.f;
#pragma unroll
            for (int ks = 0; ks < 4; ++ks) {
                acc = __builtin_amdgcn_mfma_f32_32x32x16_bf16(aHi[ks], bcur[ks], acc, 0, 0, 0);
                acc = __builtin_amdgcn_mfma_f32_32x32x16_bf16(aLo[ks], bcur[ks], acc, 0, 0, 0);
            }

            const int blk = waveRow >> 5;
#pragma unroll
            for (int i = 0; i < 16; ++i) {
                float sim = acc[i];
                int smpL = (i & 3) + 8 * (i >> 2) + 4 * h;
                int bin = binOf(sim);
                atomicAdd(&histL[(smpL >> 2) * NB + bin], 1u << (8 * (i & 3)));
                u64 mF = __ballot(sim > THRV);
                u64 mN = __ballot(kk[i] > TAU);
                if ((l & 31) == 0) {
                    int sidx = sbBase + (i & 3) + 8 * (i >> 2) + (h << 2);
                    fnpMask[(size_t)sidx * NBLK + blk] = (unsigned)(mF >> (h << 5));
                    negMask[(size_t)sidx * NBLK + blk] = (unsigned)(mN >> (h << 5));
                }
            }
        }
#pragma unroll
        for (int ks = 0; ks < 4; ++ks) bcur[ks] = bnxt[ks];
    }

    __syncthreads();
    for (int q = tid; q < 8 * NB; q += 256) {
        int g = q >> 9, bin = q & (NB - 1);
        unsigned wv = histL[g * NB + bin];
        if (!wv) continue;
        unsigned c0 = wv & 0xffu, c1 = (wv >> 8) & 0xffu;
        unsigned c2 = (wv >> 16) & 0xffu, c3 = wv >> 24;
        int sBase = sbBase + g * 4;          // even
        unsigned p01 = c0 | (c1 << 16), p23 = c2 | (c3 << 16);
        if (p01) atomicAdd(&hist_gp[(size_t)(sBase >> 1) * NB + bin], p01);
        if (p23) atomicAdd(&hist_gp[(size_t)((sBase >> 1) + 1) * NB + bin], p23);
    }
}

// ---------------------------------------------------------------- kernel C (per-sample finalize)
__global__ __launch_bounds__(BLKF, 1) void k_fin(
    const int* __restrict__ bidx,
    const unsigned* __restrict__ fnpMask, const unsigned* __restrict__ negMask,
    const unsigned* __restrict__ hist_gp, const float* __restrict__ posExp_g,
    const float* __restrict__ f1_g, const float* __restrict__ fsumF,
    const float* __restrict__ mem, const float* __restrict__ ru,
    float* __restrict__ losses)
{
    __shared__ u64 arrF[CFX];
    __shared__ unsigned fnpRow[CFX];
    __shared__ u64 negPk[CNX];
    __shared__ float negE[CNX];
    __shared__ unsigned inclPos[KNEG + 32];
    __shared__ unsigned khist[1024];
    __shared__ unsigned scr[NB];
    __shared__ float f1sh[BITD], fssh[BITD];
    __shared__ u64 winPk[TOPF];
    __shared__ unsigned exclR[TOPF];
    __shared__ float numW[TOPF];
    __shared__ u64 bndV[64];
    __shared__ unsigned bndS[64];
    __shared__ unsigned scanBuf[BLKF];
    __shared__ float redF[BLKF];
    __shared__ u64 wmaxS[BLKF / 64];
    __shared__ u64 shBest;
    __shared__ int shI[4];
    __shared__ float shNum;
    __shared__ unsigned cFsh, cNsh, bndCnt;

    const int s = blockIdx.x, tid = threadIdx.x;
    const int w8 = tid >> 6, l = tid & 63;
    const int pos = bidx[s];

    if (tid == 0) { cFsh = 0u; cNsh = 0u; bndCnt = 0u; }
    if (tid < 16) ((float4*)f1sh)[tid] = ((const float4*)&f1_g[(size_t)s * BITD])[tid];
    else if (tid < 32) ((float4*)fssh)[tid - 16] = ((const float4*)&fsumF[(size_t)s * BITD])[tid - 16];
    {
        int sh = (s & 1) * 16;
        unsigned w0 = hist_gp[(size_t)(s >> 1) * NB + tid % NB];
        if (tid < NB) scr[tid] = (w0 >> sh) & 0xffffu;
    }
    __syncthreads();

    if (tid == 0) {
        unsigned cum = 0; int beta = NB - 1;
        for (int b2 = 0; b2 < NB; ++b2) {
            cum += scr[b2];
            if (cum >= (unsigned)(RANKA + 1)) { beta = b2; break; }
        }
        shI[0] = beta;
    }

    // ---- collect fnp rows from mask
    for (int wi = tid; wi < NBLK; wi += BLKF) {
        unsigned w32 = fnpMask[(size_t)s * NBLK + wi];
        while (w32) {
            int b = __builtin_ctz(w32); w32 &= w32 - 1;
            unsigned slot = atomicAdd(&cFsh, 1u);
            if (slot < CFX) fnpRow[slot] = (unsigned)(wi * 32 + b);
        }
    }
    __syncthreads();
    unsigned cf = cFsh; if (cf > CFX) cf = CFX;

    // recompute f32 sims for fnp rows, build packed keys
    for (int i = tid; i < (int)cf; i += BLKF) {
        unsigned row = fnpRow[i];
        const float4* mr = (const float4*)&mem[(size_t)row * BITD];
        float sim = 0.f;
#pragma unroll
        for (int q = 0; q < 16; ++q) {
            float4 m4 = mr[q];
            sim += m4.x * fssh[q * 4] + m4.y * fssh[q * 4 + 1]
                 + m4.z * fssh[q * 4 + 2] + m4.w * fssh[q * 4 + 3];
        }
        arrF[i] = ((u64)__float_as_uint(sim) << 32) | (u64)(0x3FFFFu - row);
    }
    __syncthreads();

    // ---- top-20 by (sim desc, row asc): 20 argmax extractions
    for (int wi = 0; wi < TOPF; ++wi) {
        u64 m = 0;
        for (int i = tid; i < (int)cf; i += BLKF) { u64 v = arrF[i]; m = v > m ? v : m; }
#pragma unroll
        for (int off = 1; off < 64; off <<= 1) { u64 o = __shfl_xor(m, off); m = o > m ? o : m; }
        if (l == 0) wmaxS[w8] = m;
        __syncthreads();
        if (tid == 0) {
            u64 best = 0;
            for (int q = 0; q < BLKF / 64; ++q) if (wmaxS[q] > best) best = wmaxS[q];
            winPk[wi] = best; shBest = best;
        }
        __syncthreads();
        u64 best = shBest;
        if (best == 0ull) break;
        for (int i = tid; i < (int)cf; i += BLKF) if (arrF[i] == best) arrF[i] = 0ull;
        __syncthreads();
    }
    __syncthreads();
    if (tid == 0) {
        int ne = 0;
        for (int wi = 0; wi < TOPF; ++wi) {
            u64 pk = winPk[wi];
            if (pk == 0ull) break;
            unsigned row = 0x3FFFFu - (unsigned)(pk & 0x3FFFFull);
            float sim = __uint_as_float((unsigned)(pk >> 32));
            if ((int)row != pos && sim > THRV) exclR[ne++] = row;
        }
        shI[1] = ne;
    }
    for (int q = tid; q < 1024; q += BLKF) khist[q] = 0u;
    __syncthreads();
    const int beta = shI[0], ne = shI[1];

    // e-dots for valid winners (4 lanes per entry)
    {
        int grp = tid >> 2, lp = tid & 3;
        if (grp < ne) {
            unsigned row = exclR[grp];
            const float* mr = mem + (size_t)row * BITD + lp * 16;
            const float* fr = &f1sh[lp * 16];
            float part = 0.f;
#pragma unroll
            for (int m2 = 0; m2 < 16; ++m2) part = fmaf(mr[m2], fr[m2], part);
            part += __shfl_xor(part, 1);
            part += __shfl_xor(part, 2);
            if (lp == 0) {
                float fsim = part * S8T;
                numW[grp] = fsim * expf(fsim);
            }
        }
    }
    __syncthreads();
    if (tid == 0) {
        float numer = posExp_g[s];
        for (int g = 0; g < ne; ++g) numer += numW[g];
        shNum = numer;
    }
    __syncthreads();

    // ---- neg phase: scan mask, filter, recompute sim+e, append + key hist
    for (int wi = tid; wi < NBLK; wi += BLKF) {
        unsigned w32 = negMask[(size_t)s * NBLK + wi];
        while (w32) {
            int b = __builtin_ctz(w32); w32 &= w32 - 1;
            unsigned row = (unsigned)(wi * 32 + b);
            if ((int)row == pos) continue;
            bool ex = false;
            for (int q2 = 0; q2 < ne; ++q2) ex = ex || (exclR[q2] == row);
            if (ex) continue;
            float key = ru[(size_t)s * NDATA + row];
            const float4* mr = (const float4*)&mem[(size_t)row * BITD];
            float sim = 0.f, e = 0.f;
#pragma unroll
            for (int q = 0; q < 16; ++q) {
                float4 m4 = mr[q];
                sim += m4.x * fssh[q * 4] + m4.y * fssh[q * 4 + 1]
                     + m4.z * fssh[q * 4 + 2] + m4.w * fssh[q * 4 + 3];
                e += m4.x * f1sh[q * 4] + m4.y * f1sh[q * 4 + 1]
                   + m4.z * f1sh[q * 4 + 2] + m4.w * f1sh[q * 4 + 3];
            }
            if (binOf(sim) < beta) continue;
            unsigned slot = atomicAdd(&cNsh, 1u);
            if (slot < CNX) {
                negPk[slot] = ((u64)__float_as_uint(key) << 32) | (u64)(0x3FFFFu - row);
                negE[slot] = e;
                int kb = (int)((key - TAU) * KHINV);
                kb = kb < 0 ? 0 : (kb > 1023 ? 1023 : kb);
                atomicAdd(&khist[kb], 1u);
            }
        }
    }
    __syncthreads();
    unsigned cn = cNsh; if (cn > CNX) cn = CNX;

    if (tid == 0) {
        unsigned acc2 = 0; int Bs = 0;
        for (int b2 = 1023; b2 >= 0; --b2) {
            unsigned c2 = khist[b2];
            if (acc2 + c2 >= (unsigned)KNEG) { Bs = b2; break; }
            acc2 += c2;
            if (b2 == 0) Bs = 0;
        }
        shI[2] = Bs;
    }
    __syncthreads();
    const int Bstar = shI[2];

    // count strictly-above per thread
    unsigned cnt = 0;
    for (int i = tid; i < (int)cn; i += BLKF) {
        float key = __uint_as_float((unsigned)(negPk[i] >> 32));
        int kb = (int)((key - TAU) * KHINV);
        kb = kb < 0 ? 0 : (kb > 1023 ? 1023 : kb);
        if (kb > Bstar) cnt++;
    }
    scanBuf[tid] = cnt;
    __syncthreads();
    if (tid == 0) {
        unsigned run = 0;
        for (int q2 = 0; q2 < BLKF; ++q2) { unsigned t3 = scanBuf[q2]; scanBuf[q2] = run; run += t3; }
        shI[3] = (int)run;   // C1tot
    }
    __syncthreads();
    {
        unsigned off2 = scanBuf[tid];
        for (int i = tid; i < (int)cn; i += BLKF) {
            float key = __uint_as_float((unsigned)(negPk[i] >> 32));
            int kb = (int)((key - TAU) * KHINV);
            kb = kb < 0 ? 0 : (kb > 1023 ? 1023 : kb);
            if (kb > Bstar) {
                inclPos[off2++] = (unsigned)i;
            } else if (kb == Bstar) {
                unsigned sl2 = atomicAdd(&bndCnt, 1u);
                if (sl2 < 64u) { bndV[sl2] = negPk[i]; bndS[sl2] = (unsigned)i; }
            }
        }
    }
    __syncthreads();
    if (tid == 0) {
        int C1 = shI[3];
        int m = KNEG - C1;
        int bc = (int)bndCnt; if (bc > 64) bc = 64;
        if (m > bc) m = bc;
        if (m < 0) m = 0;
        for (int t2 = 0; t2 < m; ++t2) {          // exact top-m of boundary bin
            u64 best = 0; int bi = -1;
            for (int q2 = 0; q2 < bc; ++q2)
                if (bndV[q2] > best) { best = bndV[q2]; bi = q2; }
            inclPos[C1 + t2] = bndS[bi];
            bndV[bi] = 0;
        }
        shI[3] = C1 + m;   // nInc
    }
    __syncthreads();
    const int nInc = shI[3];

    float dsum = 0.f;
    for (int e2 = tid; e2 < nInc; e2 += BLKF)
        dsum += expf(negE[inclPos[e2]] * S8T);
    redF[tid] = dsum;
    __syncthreads();
    for (int st = BLKF / 2; st > 0; st >>= 1) {
        if (tid < st) redF[tid] += redF[tid + st];
        __syncthreads();
    }
    if (tid == 0) {
        float D = redF[0] + posExp_g[s];
        losses[s] = -logf(shNum / D) / (1.0f + (float)ne);
    }
}

// ---------------------------------------------------------------- small kernels
__global__ __launch_bounds__(256) void k_loss(const float* __restrict__ losses,
                                              float* __restrict__ out)
{
    __shared__ float buf[256];
    int t = threadIdx.x;
    buf[t] = losses[t];
    __syncthreads();
    for (int st = 128; st > 0; st >>= 1) {
        if (t < st) buf[t] += buf[t + st];
        __syncthreads();
    }
    if (t == 0) out[0] = buf[0] / 256.0f;
}

__global__ __launch_bounds__(256) void k_copy(const float* __restrict__ mem,
                                              float* __restrict__ out)
{
    size_t i = ((size_t)blockIdx.x * 256 + threadIdx.x) * 4;
    if (i < (size_t)NDATA * BITD) {
        float4 v = *(const float4*)&mem[i];
        out[1 + i] = v.x; out[2 + i] = v.y; out[3 + i] = v.z; out[4 + i] = v.w;
    }
}

__global__ __launch_bounds__(64) void k_scatter(const int* __restrict__ bidx,
                                                const float* __restrict__ upd,
                                                float* __restrict__ out)
{
    int s = blockIdx.x, j = threadIdx.x;
    int pos = bidx[s];
    bool last = true;
    for (int s2 = s + 1; s2 < BATCH; ++s2)
        if (bidx[s2] == pos) last = false;   // last write wins (np semantics)
    if (last) out[1 + (size_t)pos * BITD + j] = upd[s * BITD + j];
}

// ---------------------------------------------------------------- launcher
extern "C" void kernel_launch(void* const* d_in, const int* in_sizes, int n_in,
                              void* d_out, int out_size, void* d_ws, size_t ws_size,
                              hipStream_t stream)
{
    const float* iA = (const float*)d_in[0];
    const float* iB = (const float*)d_in[1];
    const float* tA = (const float*)d_in[2];
    const float* tB = (const float*)d_in[3];
    const float* mem = (const float*)d_in[4];
    const float* ru  = (const float*)d_in[5];
    const int* bidx  = (const int*)d_in[6];
    float* out = (float*)d_out;

    char* w = (char*)d_ws;
    unsigned* fnpMask = (unsigned*)w;  w += (size_t)BATCH * NBLK * 4;     // 6.4 MB
    unsigned* negMask = (unsigned*)w;  w += (size_t)BATCH * NBLK * 4;     // 6.4 MB
    unsigned short* memB = (unsigned short*)w; w += (size_t)NDATA * BITD * 2;  // 25.6 MB
    unsigned* hist_gp = (unsigned*)w;  w += (size_t)(BATCH / 2) * NB * 4; // 256 KB
    float* fsumF = (float*)w;          w += BATCH * BITD * 4;
    float* f1_g = (float*)w;           w += BATCH * BITD * 4;
    float* upd_g = (float*)w;          w += BATCH * BITD * 4;
    float* posExp_g = (float*)w;       w += BATCH * 4;
    float* losses = (float*)w;         w += BATCH * 4;
    unsigned short* fsumHi = (unsigned short*)w; w += BATCH * BITD * 2;
    unsigned short* fsumLo = (unsigned short*)w; w += BATCH * BITD * 2;

    k_prep<<<BATCH, 64, 0, stream>>>(iA, iB, tA, tB, mem, bidx, fsumHi, fsumLo,
                                     fsumF, f1_g, upd_g, posExp_g, hist_gp);
    k_pack<<<NDATA / 32, 256, 0, stream>>>(mem, memB);
    k_copy<<<(NDATA * BITD) / 4 / 256, 256, 0, stream>>>(mem, out);
    k_main<<<dim3(NCH, NSB), 256, 0, stream>>>(memB, ru, fsumHi, fsumLo,
                                               fnpMask, negMask, hist_gp);
    k_fin<<<BATCH, BLKF, 0, stream>>>(bidx, fnpMask, negMask, hist_gp, posExp_g,
                                      f1_g, fsumF, mem, ru, losses);
    k_loss<<<1, 256, 0, stream>>>(losses, out);
    k_scatter<<<BATCH, 64, 0, stream>>>(bidx, upd_g, out);
}